// Round 1
// baseline (90.610 us; speedup 1.0000x reference)
//
#include <hip/hip_runtime.h>

#define SQ_ 512      // queries
#define MQ_ 256      // candidates per query
#define DQ_ 1024     // embedding dim
#define KQ_ 5
#define EPSQ 1e-8f

// ---------------- kernel 1: query norms ----------------
__global__ void qnorm_kernel(const float* __restrict__ q, float* __restrict__ qn) {
    int wave = (int)((blockIdx.x * blockDim.x + threadIdx.x) >> 6);
    int lane = threadIdx.x & 63;
    if (wave >= SQ_) return;
    const float4* row = (const float4*)(q + (size_t)wave * DQ_);
    float sq = 0.f;
#pragma unroll
    for (int i = 0; i < DQ_ / 4 / 64; ++i) {
        float4 v = row[lane + i * 64];
        sq += v.x * v.x + v.y * v.y + v.z * v.z + v.w * v.w;
    }
#pragma unroll
    for (int off = 32; off; off >>= 1) sq += __shfl_xor(sq, off);
    if (lane == 0) qn[wave] = fmaxf(sqrtf(sq), EPSQ);
}

// ---------------- kernel 2: cosine sims + gathered labels ----------------
__global__ void sim_kernel(const float* __restrict__ q,
                           const float* __restrict__ bank,
                           const float* __restrict__ labels,
                           const int* __restrict__ bidx,
                           const float* __restrict__ qn,
                           float* __restrict__ sims,
                           float* __restrict__ slab) {
    long long gw = (long long)(blockIdx.x * (long long)blockDim.x + threadIdx.x) >> 6;
    int lane = threadIdx.x & 63;
    if (gw >= (long long)SQ_ * MQ_) return;
    int s = (int)(gw >> 8);          // gw / MQ_
    int idx = bidx[gw];
    const float4* crow = (const float4*)(bank + (long long)idx * DQ_);
    const float4* qrow = (const float4*)(q + (size_t)s * DQ_);
    float dot = 0.f, sq = 0.f;
#pragma unroll
    for (int i = 0; i < 4; ++i) {
        int j = lane + i * 64;
        float4 c = crow[j];
        float4 qq = qrow[j];
        dot += c.x * qq.x + c.y * qq.y + c.z * qq.z + c.w * qq.w;
        sq  += c.x * c.x + c.y * c.y + c.z * c.z + c.w * c.w;
    }
#pragma unroll
    for (int off = 32; off; off >>= 1) {
        dot += __shfl_xor(dot, off);
        sq  += __shfl_xor(sq, off);
    }
    if (lane == 0) {
        float cn = fmaxf(sqrtf(sq), EPSQ);
        sims[gw] = dot / (qn[s] * cn);
        slab[gw] = labels[idx];
    }
}

// ---------------- kernel 3: top-5 + mean + round ----------------
__global__ void topk_kernel(const float* __restrict__ sims,
                            const float* __restrict__ slab,
                            float* __restrict__ out) {
    int gw = (int)((blockIdx.x * blockDim.x + threadIdx.x) >> 6);
    int lane = threadIdx.x & 63;
    if (gw >= SQ_) return;
    const float* srow = sims + (size_t)gw * MQ_;
    const float* lrow = slab + (size_t)gw * MQ_;
    float v[4];
#pragma unroll
    for (int i = 0; i < 4; ++i) v[i] = srow[lane + i * 64];
    float sum = 0.f;
    for (int t = 0; t < KQ_; ++t) {
        // local argmax, tie -> smallest index (strict > keeps lowest i)
        float bv = v[0];
        int bi = lane;
#pragma unroll
        for (int i = 1; i < 4; ++i) {
            if (v[i] > bv) { bv = v[i]; bi = lane + i * 64; }
        }
        // wave argmax, tie -> smallest index (matches jax.lax.top_k stability)
#pragma unroll
        for (int off = 32; off; off >>= 1) {
            float ov = __shfl_xor(bv, off);
            int oi = __shfl_xor(bi, off);
            if (ov > bv || (ov == bv && oi < bi)) { bv = ov; bi = oi; }
        }
        sum += lrow[bi];                 // broadcast load, same addr all lanes
        if ((bi & 63) == lane && (bi >> 6) >= 0) {
            // clear the winner so next round picks the next-best
            v[bi >> 6] = -2.0f;          // sims are in [-1, 1]
        }
    }
    if (lane == 0) out[gw] = rintf(sum / (float)KQ_);
}

extern "C" void kernel_launch(void* const* d_in, const int* in_sizes, int n_in,
                              void* d_out, int out_size, void* d_ws, size_t ws_size,
                              hipStream_t stream) {
    const float* q      = (const float*)d_in[0];   // [S, D]
    const float* bank   = (const float*)d_in[1];   // [N, D]
    const float* labels = (const float*)d_in[2];   // [N]
    const int*   bidx   = (const int*)d_in[3];     // [S, M] (int64 -> int32 by harness)
    // d_in[4] = k (always 5)

    float* out = (float*)d_out;                    // [S]

    // workspace layout
    float* sims = (float*)d_ws;                         // S*M floats = 512 KiB
    float* slab = sims + (size_t)SQ_ * MQ_;             // S*M floats = 512 KiB
    float* qn   = slab + (size_t)SQ_ * MQ_;             // S floats

    // kernel 1: 512 waves, 4 waves/block -> 128 blocks
    qnorm_kernel<<<SQ_ / 4, 256, 0, stream>>>(q, qn);

    // kernel 2: S*M waves, 4 waves/block -> 32768 blocks
    sim_kernel<<<(SQ_ * MQ_) / 4, 256, 0, stream>>>(q, bank, labels, bidx, qn, sims, slab);

    // kernel 3: 512 waves -> 128 blocks
    topk_kernel<<<SQ_ / 4, 256, 0, stream>>>(sims, slab, out);
}